// Round 7
// baseline (131.336 us; speedup 1.0000x reference)
//
#include <hip/hip_runtime.h>

// B=4096, F0=39, D=16, L=(128,128), H1=64
// Round-7: r6 topology, f16 datapath.
//  - mfma_f32_32x32x16_f16, M=32 = 2 batches x 16 d, N=128, K=(i,j).
//  - A-frags built with v_pk_mul_f16 from packed-f16 xv registers (16 VALU/chunk,
//    was ~80 with bf16 shift/and/or packing) — the r6 VALU bottleneck.
//  - B: f16 weights repacked to exact frag order in d_ws, global->VGPR,
//    copy-free distance-2 prefetch, no K-loop barriers.
//  - h stored f16 in LDS; x staged f16.
// Layouts (verified):
//  A: lane holds A[m=lane&31][k=(lane>>5)*8+t]
//  B: lane holds B[k=(lane>>5)*8+t][n=lane&31]
//  D: lane holds D[row=(r&3)+8*(r>>2)+4*(lane>>5)][col=lane&31]
// Repacked B layout (BYTES): ch*8192 + kh*4096 + cg*1024 + lane*16  (8 f16 per lane)
//  L0 ch=ig*5+jg (ig<10,jg<5): i=ig*4+kh*2+half, j=jg*8+t, zero-pad i,j>=39.
//  L1 ch=50+jg*5+ig (jg<16,ig<5): j=jg*4+kh*2+half, i=ig*8+t, zero-pad i>=39.
// Total: 130 chunks * 8192 B = 1,064,960 B of d_ws.

typedef _Float16 h2    __attribute__((ext_vector_type(2)));
typedef _Float16 f16x8 __attribute__((ext_vector_type(8)));
typedef __attribute__((ext_vector_type(16))) float f32x16;

// ---------------- weight repack: coalesced reads, f16 frag stores ----------------
__global__ __launch_bounds__(256)
void CIN_repack(const float* __restrict__ f0, const float* __restrict__ f1,
                uint4* __restrict__ ws)
{
    const int tid  = blockIdx.x * 256 + threadIdx.x;   // 66560 total
    const int n    = tid & 127;
    const int slot = tid >> 7;                          // 0..519
    const int half = slot & 1;
    const int kh   = (slot >> 1) & 1;
    const int ch   = slot >> 2;                         // 0..129
    float v[8];
    if (ch < 50) {
        const int ig = ch / 5, jg = ch - ig * 5;
        const int i = ig * 4 + kh * 2 + half;           // 0..39
        const bool iok = (i < 39);
#pragma unroll
        for (int t = 0; t < 8; ++t) {
            const int j = jg * 8 + t;                   // 0..39
            v[t] = (iok && j < 39) ? f0[(i * 39 + j) * 128 + n] : 0.f;
        }
    } else {
        const int c1 = ch - 50;
        const int jg = c1 / 5, ig = c1 - jg * 5;
        const int j = jg * 4 + kh * 2 + half;           // 0..63
#pragma unroll
        for (int t = 0; t < 8; ++t) {
            const int i = ig * 8 + t;                   // 0..39
            v[t] = (i < 39) ? f1[(i * 64 + j) * 128 + n] : 0.f;
        }
    }
    union { h2 h[4]; uint4 q; } pk;
#pragma unroll
    for (int t = 0; t < 4; ++t)
        pk.h[t] = h2{(_Float16)v[2 * t], (_Float16)v[2 * t + 1]};   // RNE cvt
    const int lane = half * 32 + (n & 31);
    const int cg   = n >> 5;
    ws[ch * 512 + kh * 256 + cg * 64 + lane] = pk.q;
}

// ---------------- main ----------------
__global__ __launch_bounds__(256, 2)
void CIN_main(const float* __restrict__ x,
              const char* __restrict__ wsB,
              const float* __restrict__ dw,
              const float* __restrict__ db,
              float* __restrict__ out)
{
    __shared__ __align__(16) _Float16 xsH[8][16][64];  // [bb][d][i], i=39 zeroed, 40..63 unused
    __shared__ __align__(4)  _Float16 hsH[8][64][18];  // [bb][j][d], pad 18
    __shared__ float dws[192];
    __shared__ float red[2][2][4];

    const int tid  = threadIdx.x;
    const int w    = tid >> 6;
    const int lane = tid & 63;
    const int g    = w & 1;        // batch-group (4 batches)
    const int hh   = w >> 1;       // col-half (n 0..63 / 64..127)
    const int half = lane >> 5;
    const int d    = lane & 15;
    const int bsel = (lane >> 4) & 1;
    const int g4   = g * 4;

    // B frag base: rebase +2560 so all 4 offsets {-2560,-1536,+1536,+2560} fit imm13
    const char* wbase = wsB + lane * 16 + hh * 2048 + 2560;
    f16x8 Bb[2][2][2];             // [phase][kh][c]
    auto loadBg = [&](int ch, f16x8 (&B)[2][2]) {
        const char* p0 = wbase + (size_t)ch * 8192;
        B[0][0] = *(const f16x8*)(p0 - 2560);
        B[0][1] = *(const f16x8*)(p0 - 1536);
        B[1][0] = *(const f16x8*)(p0 + 1536);
        B[1][1] = *(const f16x8*)(p0 + 2560);
    };

    loadBg(0, Bb[0]);              // issued before x staging: latency hidden
    loadBg(1, Bb[1]);

    // ---- stage x for 8 batches as f16: 1248 float4 ----
    const float4* xg4 = (const float4*)(x + (size_t)blockIdx.x * 8 * 624);
    for (int e4 = tid; e4 < 1248; e4 += 256) {
        float4 v = xg4[e4];
        int bb = e4 / 156, r = e4 - bb * 156;
        int i = r >> 2, d0 = (r & 3) * 4;
        xsH[bb][d0 + 0][i] = (_Float16)v.x; xsH[bb][d0 + 1][i] = (_Float16)v.y;
        xsH[bb][d0 + 2][i] = (_Float16)v.z; xsH[bb][d0 + 3][i] = (_Float16)v.w;
    }
    if (tid < 128) { int bb = tid >> 4, dd = tid & 15; xsH[bb][dd][39] = (_Float16)0.f; }
    if (tid < 192) dws[tid] = dw[tid];
    __syncthreads();

    // ---- xv: lane's own-batch x row, PACKED f16 registers (40 values = 20 dwords/batch) ----
    h2 xv[2][20];
#pragma unroll
    for (int p = 0; p < 2; ++p) {
        const uint4* src = (const uint4*)&xsH[g4 + p * 2 + bsel][d][0];  // 128B rows, aligned
#pragma unroll
        for (int q5 = 0; q5 < 5; ++q5) {
            union { uint4 q; h2 h[4]; } u;
            u.q = src[q5];                      // halfs 8*q5 .. 8*q5+7  (covers 0..39 exactly)
#pragma unroll
            for (int t = 0; t < 4; ++t) xv[p][q5 * 4 + t] = u.h[t];
        }
    }

    f32x16 acc[2][2];
#pragma unroll
    for (int p = 0; p < 2; ++p)
#pragma unroll
        for (int c = 0; c < 2; ++c)
#pragma unroll
            for (int r = 0; r < 16; ++r) acc[p][c][r] = 0.f;

    h2 xiv2[2][2];

    // ---------------- layer 0: 5 outer x 10 unrolled chunks ----------------
#pragma unroll 1
    for (int o = 0; o < 5; ++o) {
#pragma unroll
        for (int u = 0; u < 10; ++u) {
            const int ch = o * 10 + u;
            const int jg = u % 5;
            if (jg == 0) {
                const int ib = (o * 2 + u / 5) * 4;
#pragma unroll
                for (int p = 0; p < 2; ++p)
#pragma unroll
                    for (int kh = 0; kh < 2; ++kh) {
                        _Float16 s = xsH[g4 + p * 2 + bsel][d][ib + kh * 2 + half];
                        xiv2[p][kh] = h2{s, s};
                    }
            }
            f16x8 A[2][2];
#pragma unroll
            for (int p = 0; p < 2; ++p)
#pragma unroll
                for (int kh = 0; kh < 2; ++kh) {
                    union { h2 h[4]; f16x8 v; } a;
#pragma unroll
                    for (int q = 0; q < 4; ++q)
                        a.h[q] = xiv2[p][kh] * xv[p][jg * 4 + q];   // v_pk_mul_f16
                    A[p][kh] = a.v;
                }
#pragma unroll
            for (int p = 0; p < 2; ++p)
#pragma unroll
                for (int c = 0; c < 2; ++c) {
                    acc[p][c] = __builtin_amdgcn_mfma_f32_32x32x16_f16(A[p][0], Bb[u & 1][0][c], acc[p][c], 0, 0, 0);
                    acc[p][c] = __builtin_amdgcn_mfma_f32_32x32x16_f16(A[p][1], Bb[u & 1][1][c], acc[p][c], 0, 0, 0);
                }
            loadBg(ch + 2, Bb[u & 1]);   // max ch+2 = 51 — in bounds
        }
    }

    // ---------------- layer-0 epilogue ----------------
    float cs[4] = {0.f, 0.f, 0.f, 0.f};
    if (hh == 0) {
#pragma unroll
        for (int p = 0; p < 2; ++p)
#pragma unroll
            for (int c = 0; c < 2; ++c)
#pragma unroll
                for (int r = 0; r < 16; r += 2) {       // rows r,r+1 adjacent, same bb, even d
                    const int row = (r & 3) + 8 * (r >> 2) + 4 * half;
                    h2 pr = h2{(_Float16)fmaxf(acc[p][c][r],     0.f),
                               (_Float16)fmaxf(acc[p][c][r + 1], 0.f)};
                    *(h2*)&hsH[g4 + p * 2 + (row >> 4)][c * 32 + (lane & 31)][row & 15] = pr;
                }
    } else {
#pragma unroll
        for (int p = 0; p < 2; ++p)
#pragma unroll
            for (int c = 0; c < 2; ++c) {
                const float dwv = dws[c * 32 + (lane & 31)];   // dw[n-64]
#pragma unroll
                for (int r = 0; r < 16; ++r) {
                    const int row = (r & 3) + 8 * (r >> 2) + 4 * half;
                    cs[p * 2 + (row >> 4)] += fmaxf(acc[p][c][r], 0.f) * dwv;
                }
            }
    }
#pragma unroll
    for (int p = 0; p < 2; ++p)
#pragma unroll
        for (int c = 0; c < 2; ++c)
#pragma unroll
            for (int r = 0; r < 16; ++r) acc[p][c][r] = 0.f;
    __syncthreads();   // h visible to all waves

    // ---------------- layer 1: 8 outer x 10 unrolled chunks (50..129) ----------------
    // phase continuity: chunk 50 -> u=0 -> Bb[0] (prefetched at o=4,u=8) OK
#pragma unroll 1
    for (int o2 = 0; o2 < 8; ++o2) {
#pragma unroll
        for (int u = 0; u < 10; ++u) {
            const int ch = 50 + o2 * 10 + u;
            const int ig2 = u % 5;
            if (ig2 == 0) {
                const int jb = (o2 * 2 + u / 5) * 4;
#pragma unroll
                for (int p = 0; p < 2; ++p)
#pragma unroll
                    for (int kh = 0; kh < 2; ++kh) {
                        _Float16 s = hsH[g4 + p * 2 + bsel][jb + kh * 2 + half][d];
                        xiv2[p][kh] = h2{s, s};
                    }
            }
            f16x8 A[2][2];
#pragma unroll
            for (int p = 0; p < 2; ++p)
#pragma unroll
                for (int kh = 0; kh < 2; ++kh) {
                    union { h2 h[4]; f16x8 v; } a;
#pragma unroll
                    for (int q = 0; q < 4; ++q)
                        a.h[q] = xiv2[p][kh] * xv[p][ig2 * 4 + q];
                    A[p][kh] = a.v;
                }
#pragma unroll
            for (int p = 0; p < 2; ++p)
#pragma unroll
                for (int c = 0; c < 2; ++c) {
                    acc[p][c] = __builtin_amdgcn_mfma_f32_32x32x16_f16(A[p][0], Bb[u & 1][0][c], acc[p][c], 0, 0, 0);
                    acc[p][c] = __builtin_amdgcn_mfma_f32_32x32x16_f16(A[p][1], Bb[u & 1][1][c], acc[p][c], 0, 0, 0);
                }
            int chn = ch + 2; if (chn > 129) chn = 129;
            loadBg(chn, Bb[u & 1]);
        }
    }

    // ---------------- layer-1 epilogue + reduction ----------------
#pragma unroll
    for (int p = 0; p < 2; ++p)
#pragma unroll
        for (int c = 0; c < 2; ++c) {
            const float dwv = dws[64 + (2 * hh + c) * 32 + (lane & 31)];
#pragma unroll
            for (int r = 0; r < 16; ++r) {
                const int row = (r & 3) + 8 * (r >> 2) + 4 * half;
                cs[p * 2 + (row >> 4)] += fmaxf(acc[p][c][r], 0.f) * dwv;
            }
        }
#pragma unroll
    for (int rr = 0; rr < 4; ++rr)
#pragma unroll
        for (int off = 32; off > 0; off >>= 1)
            cs[rr] += __shfl_xor(cs[rr], off, 64);
    if (lane == 0) {
#pragma unroll
        for (int rr = 0; rr < 4; ++rr) red[g][hh][rr] = cs[rr];
    }
    __syncthreads();
    if (tid < 8) {
        const int g2 = tid >> 2, rr = tid & 3;
        out[blockIdx.x * 8 + g2 * 4 + rr] = red[g2][0][rr] + red[g2][1][rr] + db[0];
    }
}

extern "C" void kernel_launch(void* const* d_in, const int* in_sizes, int n_in,
                              void* d_out, int out_size, void* d_ws, size_t ws_size,
                              hipStream_t stream)
{
    const float* x  = (const float*)d_in[0];
    const float* f0 = (const float*)d_in[1];
    const float* f1 = (const float*)d_in[2];
    const float* dw = (const float*)d_in[3];
    const float* db = (const float*)d_in[4];
    float* out = (float*)d_out;

    CIN_repack<<<dim3(260), dim3(256), 0, stream>>>(f0, f1, (uint4*)d_ws);
    CIN_main<<<dim3(512), dim3(256), 0, stream>>>(x, (const char*)d_ws, dw, db, out);
}

// Round 8
// 125.113 us; speedup vs baseline: 1.0497x; 1.0497x over previous
//
#include <hip/hip_runtime.h>

// B=4096, F0=39, D=16, L=(128,128), H1=64
// Round-8: r7 f16 datapath; wave remap to kill B-read duplication.
//  - Wave w (0..3) owns ALL 8 block batches (4 M-tiles p, batch = 2p+bsel) and
//    col-quarter n in [w*32, w*32+32). Block B reads are fully disjoint:
//    8 KB/chunk/block (was 16 KB) -> L1 delivery ~14 us/CU < MFMA floor 29 us.
//  - mfma_f32_32x32x16_f16; A built with v_pk_mul_f16 from packed-f16 xv regs.
//  - B: f16 frag-order in d_ws, global->VGPR, copy-free distance-2 prefetch, no K barriers.
//  - xsH padded: i-stride 72 halves + 8-half batch skew (16-way -> ~2-way conflicts).
// Layouts (verified):
//  A: lane holds A[m=lane&31][k=(lane>>5)*8+t]
//  B: lane holds B[k=(lane>>5)*8+t][n=lane&31]
//  D: lane holds D[row=(r&3)+8*(r>>2)+4*(lane>>5)][col=lane&31]
// Repacked B layout (BYTES): ch*8192 + kh*4096 + cg*1024 + lane*16  (8 f16 per lane)
//  L0 ch=ig*5+jg (ig<10,jg<5): i=ig*4+kh*2+half, j=jg*8+t, zero-pad i,j>=39.
//  L1 ch=50+jg*5+ig (jg<16,ig<5): j=jg*4+kh*2+half, i=ig*8+t, zero-pad i>=39.
// Total: 130 chunks * 8192 B = 1,064,960 B of d_ws.

typedef _Float16 h2    __attribute__((ext_vector_type(2)));
typedef _Float16 f16x8 __attribute__((ext_vector_type(8)));
typedef __attribute__((ext_vector_type(16))) float f32x16;

#define XBB 1160   // per-batch halfs in xsH: 16*72 + 8 skew

// ---------------- weight repack: coalesced reads, f16 frag stores ----------------
__global__ __launch_bounds__(256)
void CIN_repack(const float* __restrict__ f0, const float* __restrict__ f1,
                uint4* __restrict__ ws)
{
    const int tid  = blockIdx.x * 256 + threadIdx.x;   // 66560 total
    const int n    = tid & 127;
    const int slot = tid >> 7;                          // 0..519
    const int half = slot & 1;
    const int kh   = (slot >> 1) & 1;
    const int ch   = slot >> 2;                         // 0..129
    float v[8];
    if (ch < 50) {
        const int ig = ch / 5, jg = ch - ig * 5;
        const int i = ig * 4 + kh * 2 + half;           // 0..39
        const bool iok = (i < 39);
#pragma unroll
        for (int t = 0; t < 8; ++t) {
            const int j = jg * 8 + t;                   // 0..39
            v[t] = (iok && j < 39) ? f0[(i * 39 + j) * 128 + n] : 0.f;
        }
    } else {
        const int c1 = ch - 50;
        const int jg = c1 / 5, ig = c1 - jg * 5;
        const int j = jg * 4 + kh * 2 + half;           // 0..63
#pragma unroll
        for (int t = 0; t < 8; ++t) {
            const int i = ig * 8 + t;                   // 0..39
            v[t] = (i < 39) ? f1[(i * 64 + j) * 128 + n] : 0.f;
        }
    }
    union { h2 h[4]; uint4 q; } pk;
#pragma unroll
    for (int t = 0; t < 4; ++t)
        pk.h[t] = h2{(_Float16)v[2 * t], (_Float16)v[2 * t + 1]};
    const int lane = half * 32 + (n & 31);
    const int cg   = n >> 5;
    ws[ch * 512 + kh * 256 + cg * 64 + lane] = pk.q;
}

// ---------------- main ----------------
__global__ __launch_bounds__(256, 2)
void CIN_main(const float* __restrict__ x,
              const char* __restrict__ wsB,
              const float* __restrict__ dw,
              const float* __restrict__ db,
              float* __restrict__ out)
{
    __shared__ __align__(16) _Float16 xsH[8 * XBB];    // [bb]: 16 rows of 72 (i<=39 used)
    __shared__ __align__(4)  _Float16 hsH[8][64][18];  // [bb][j][d]
    __shared__ float dws[192];
    __shared__ float red[4][8];

    const int tid  = threadIdx.x;
    const int w    = tid >> 6;     // col-quarter: n in [w*32, w*32+32)
    const int lane = tid & 63;
    const int half = lane >> 5;
    const int d    = lane & 15;
    const int bsel = (lane >> 4) & 1;
    const int col  = lane & 31;

    // B frag base: this wave's col-group = w. Rebase +2048: offsets {-2048,+2048} fit imm13.
    const char* wbase = wsB + lane * 16 + w * 1024 + 2048;
    f16x8 Bb[2][2];                // [phase][kh]
    auto loadBg = [&](int ch, f16x8 (&B)[2]) {
        const char* p0 = wbase + (size_t)ch * 8192;
        B[0] = *(const f16x8*)(p0 - 2048);
        B[1] = *(const f16x8*)(p0 + 2048);
    };

    loadBg(0, Bb[0]);              // issued before x staging: latency hidden
    loadBg(1, Bb[1]);

    // ---- stage x for 8 batches as f16 ----
    const float4* xg4 = (const float4*)(x + (size_t)blockIdx.x * 8 * 624);
    for (int e4 = tid; e4 < 1248; e4 += 256) {
        float4 v = xg4[e4];
        int bb = e4 / 156, r = e4 - bb * 156;
        int i = r >> 2, d0 = (r & 3) * 4;
        _Float16* bp = xsH + bb * XBB + i;
        bp[(d0 + 0) * 72] = (_Float16)v.x; bp[(d0 + 1) * 72] = (_Float16)v.y;
        bp[(d0 + 2) * 72] = (_Float16)v.z; bp[(d0 + 3) * 72] = (_Float16)v.w;
    }
    if (tid < 128) { int bb = tid >> 4, dd = tid & 15; xsH[bb * XBB + dd * 72 + 39] = (_Float16)0.f; }
    if (tid < 192) dws[tid] = dw[tid];
    __syncthreads();

    // ---- xv: per M-tile p, lane's batch row x[2p+bsel, :, d], packed f16 (40 vals) ----
    h2 xv[4][20];
#pragma unroll
    for (int p = 0; p < 4; ++p) {
        const uint4* src = (const uint4*)(xsH + (p * 2 + bsel) * XBB + d * 72);
#pragma unroll
        for (int q5 = 0; q5 < 5; ++q5) {
            union { uint4 q; h2 h[4]; } u;
            u.q = src[q5];                      // halfs 8*q5 .. 8*q5+7 (covers 0..39)
#pragma unroll
            for (int t = 0; t < 4; ++t) xv[p][q5 * 4 + t] = u.h[t];
        }
    }

    f32x16 acc[4];
#pragma unroll
    for (int p = 0; p < 4; ++p)
#pragma unroll
        for (int r = 0; r < 16; ++r) acc[p][r] = 0.f;

    h2 xiv2[4][2];

    // ---------------- layer 0: 5 outer x 10 unrolled chunks ----------------
#pragma unroll 1
    for (int o = 0; o < 5; ++o) {
#pragma unroll
        for (int u = 0; u < 10; ++u) {
            const int ch = o * 10 + u;
            const int jg = u % 5;
            if (jg == 0) {
                const int ib = (o * 2 + u / 5) * 4;
#pragma unroll
                for (int p = 0; p < 4; ++p)
#pragma unroll
                    for (int kh = 0; kh < 2; ++kh) {
                        _Float16 s = xsH[(p * 2 + bsel) * XBB + d * 72 + ib + kh * 2 + half];
                        xiv2[p][kh] = h2{s, s};
                    }
            }
#pragma unroll
            for (int p = 0; p < 4; ++p) {
                union { h2 h[4]; f16x8 v; } a0, a1;
#pragma unroll
                for (int q = 0; q < 4; ++q) {
                    a0.h[q] = xiv2[p][0] * xv[p][jg * 4 + q];   // v_pk_mul_f16
                    a1.h[q] = xiv2[p][1] * xv[p][jg * 4 + q];
                }
                acc[p] = __builtin_amdgcn_mfma_f32_32x32x16_f16(a0.v, Bb[u & 1][0], acc[p], 0, 0, 0);
                acc[p] = __builtin_amdgcn_mfma_f32_32x32x16_f16(a1.v, Bb[u & 1][1], acc[p], 0, 0, 0);
            }
            loadBg(ch + 2, Bb[u & 1]);   // max ch+2 = 51 — in bounds
        }
    }

    // ---------------- layer-0 epilogue ----------------
    float cs[8] = {0.f, 0.f, 0.f, 0.f, 0.f, 0.f, 0.f, 0.f};
    if (w < 2) {
        // n = w*32+col < 64 -> h = relu(z0) into LDS
#pragma unroll
        for (int p = 0; p < 4; ++p)
#pragma unroll
            for (int r = 0; r < 16; r += 2) {           // rows r,r+1 adjacent, row even
                const int row = (r & 3) + 8 * (r >> 2) + 4 * half;
                h2 pr = h2{(_Float16)fmaxf(acc[p][r],     0.f),
                           (_Float16)fmaxf(acc[p][r + 1], 0.f)};
                *(h2*)&hsH[p * 2 + (row >> 4)][w * 32 + col][row & 15] = pr;
            }
    } else {
        const float dwv = dws[(w - 2) * 32 + col];      // dw[n-64]
#pragma unroll
        for (int p = 0; p < 4; ++p)
#pragma unroll
            for (int r = 0; r < 16; ++r) {
                const int row = (r & 3) + 8 * (r >> 2) + 4 * half;
                cs[p * 2 + (row >> 4)] += fmaxf(acc[p][r], 0.f) * dwv;
            }
    }
#pragma unroll
    for (int p = 0; p < 4; ++p)
#pragma unroll
        for (int r = 0; r < 16; ++r) acc[p][r] = 0.f;
    __syncthreads();   // h visible to all waves

    // ---------------- layer 1: 8 outer x 10 unrolled chunks (50..129) ----------------
    // phase continuity: chunk 50 -> u=0 -> Bb[0] (prefetched at o=4,u=8) OK
#pragma unroll 1
    for (int o2 = 0; o2 < 8; ++o2) {
#pragma unroll
        for (int u = 0; u < 10; ++u) {
            const int ch = 50 + o2 * 10 + u;
            const int ig2 = u % 5;
            if (ig2 == 0) {
                const int jb = (o2 * 2 + u / 5) * 4;
#pragma unroll
                for (int p = 0; p < 4; ++p)
#pragma unroll
                    for (int kh = 0; kh < 2; ++kh) {
                        _Float16 s = hsH[p * 2 + bsel][jb + kh * 2 + half][d];
                        xiv2[p][kh] = h2{s, s};
                    }
            }
#pragma unroll
            for (int p = 0; p < 4; ++p) {
                union { h2 h[4]; f16x8 v; } a0, a1;
#pragma unroll
                for (int q = 0; q < 4; ++q) {
                    a0.h[q] = xiv2[p][0] * xv[p][ig2 * 4 + q];
                    a1.h[q] = xiv2[p][1] * xv[p][ig2 * 4 + q];
                }
                acc[p] = __builtin_amdgcn_mfma_f32_32x32x16_f16(a0.v, Bb[u & 1][0], acc[p], 0, 0, 0);
                acc[p] = __builtin_amdgcn_mfma_f32_32x32x16_f16(a1.v, Bb[u & 1][1], acc[p], 0, 0, 0);
            }
            int chn = ch + 2; if (chn > 129) chn = 129;
            loadBg(chn, Bb[u & 1]);
        }
    }

    // ---------------- layer-1 epilogue + reduction ----------------
    {
        const float dwv = dws[64 + w * 32 + col];
#pragma unroll
        for (int p = 0; p < 4; ++p)
#pragma unroll
            for (int r = 0; r < 16; ++r) {
                const int row = (r & 3) + 8 * (r >> 2) + 4 * half;
                cs[p * 2 + (row >> 4)] += fmaxf(acc[p][r], 0.f) * dwv;
            }
    }
#pragma unroll
    for (int rr = 0; rr < 8; ++rr)
#pragma unroll
        for (int off = 32; off > 0; off >>= 1)
            cs[rr] += __shfl_xor(cs[rr], off, 64);
    if (lane == 0) {
#pragma unroll
        for (int rr = 0; rr < 8; ++rr) red[w][rr] = cs[rr];
    }
    __syncthreads();
    if (tid < 8)
        out[blockIdx.x * 8 + tid] = red[0][tid] + red[1][tid] + red[2][tid] + red[3][tid] + db[0];
}

extern "C" void kernel_launch(void* const* d_in, const int* in_sizes, int n_in,
                              void* d_out, int out_size, void* d_ws, size_t ws_size,
                              hipStream_t stream)
{
    const float* x  = (const float*)d_in[0];
    const float* f0 = (const float*)d_in[1];
    const float* f1 = (const float*)d_in[2];
    const float* dw = (const float*)d_in[3];
    const float* db = (const float*)d_in[4];
    float* out = (float*)d_out;

    CIN_repack<<<dim3(260), dim3(256), 0, stream>>>(f0, f1, (uint4*)d_ws);
    CIN_main<<<dim3(512), dim3(256), 0, stream>>>(x, (const char*)d_ws, dw, db, out);
}